// Round 7
// baseline (33.544 us; speedup 1.0000x reference)
//
#include <hip/hip_runtime.h>
#include <hip/hip_bf16.h>

#define BLOCK 256
#define NWAVES 4
#define WPAIRS 64                    // pairs per wave-tile (1 per lane)
#define WTILE_FLOATS (WPAIRS * 9)    // 576 floats per input per wave-tile
#define WBUF_FLOATS (2 * WTILE_FLOATS) // 1152: D1|D2 regions of one buffer

__device__ __forceinline__ float frcp(float x) { return __builtin_amdgcn_rcpf(x); }
__device__ __forceinline__ float fsqrt(float x) { return __builtin_amdgcn_sqrtf(x); }

// fast acos: Abramowitz-Stegun 4.4.45, abs err ~6.7e-5 rad
__device__ __forceinline__ float facos(float x) {
    float ax = fabsf(x);
    float sq = fsqrt(fmaxf(1.0f - ax, 0.0f));
    float poly = fmaf(fmaf(fmaf(-0.0187293f, ax, 0.0742610f), ax, -0.2121144f),
                      ax, 1.5707288f);
    float ac = sq * poly;
    return (x < 0.0f) ? (3.14159274f - ac) : ac;
}

// logm of a symmetric 3x3 SPD matrix, 6 unique entries {00,01,02,11,12,22}.
// Newton divided differences with clamped denominators: ONE rcp for all three
// dd terms (vs 3-6). Interpolant passes through the nodes regardless, so
// clamping costs ~1e-2 worst-case on near-degenerate spectra - irrelevant at
// the 0.125 mean threshold.
__device__ __forceinline__ void logm3(const float m[6], float L[6]) {
    float a00 = m[0], a01 = m[1], a02 = m[2];
    float a11 = m[3], a12 = m[4], a22 = m[5];

    float q  = (a00 + a11 + a22) * (1.0f / 3.0f);
    float b00 = a00 - q, b11 = a11 - q, b22 = a22 - q;
    float p2 = b00*b00 + b11*b11 + b22*b22
             + 2.0f * (a01*a01 + a02*a02 + a12*a12);
    float p  = fsqrt(p2 * (1.0f / 6.0f));
    p = fmaxf(p, 1e-12f);
    float ip = frcp(p);
    float detB = b00*(b11*b22 - a12*a12)
               - a01*(a01*b22 - a12*a02)
               + a02*(a01*a12 - b11*a02);
    float ip3 = ip * ip * ip;
    float r = fminf(fmaxf(0.5f * detB * ip3, -1.0f), 1.0f);
    float phi = facos(r) * (1.0f / 3.0f);
    float sph = __sinf(phi), cph = __cosf(phi);
    float whi = q + 2.0f * p * cph;
    float wlo = q - p * (cph + 1.7320508f * sph);
    float wmid = 3.0f * q - whi - wlo;
    float w0 = fmaxf(wlo,  1e-8f);
    float w1 = fmaxf(wmid, 1e-8f);
    float w2 = fmaxf(whi,  1e-8f);

    float l0 = __logf(w0), l1 = __logf(w1), l2 = __logf(w2);
    float e = 1e-4f * w2;
    float d01 = fmaxf(w1 - w0, e);
    float d12 = fmaxf(w2 - w1, e);
    float d02 = fmaxf(w2 - w0, e);
    float rP = frcp(d01 * d12 * d02);          // single reciprocal
    float dd01 = (l1 - l0) * (d12 * d02) * rP; // = (l1-l0)/d01
    float dd12 = (l2 - l1) * (d01 * d02) * rP; // = (l2-l1)/d12
    float dd012 = (dd12 - dd01) * (d01 * d12) * rP; // = (dd12-dd01)/d02
    float k2 = dd012;
    float k1 = dd01 - dd012 * (w0 + w1);
    float k0 = l0 - dd01 * w0 + dd012 * (w0 * w1);

    float s00 = a00*a00 + a01*a01 + a02*a02;
    float s01 = a00*a01 + a01*a11 + a02*a12;
    float s02 = a00*a02 + a01*a12 + a02*a22;
    float s11 = a01*a01 + a11*a11 + a12*a12;
    float s12 = a01*a02 + a11*a12 + a12*a22;
    float s22 = a02*a02 + a12*a12 + a22*a22;

    L[0] = k0 + k1*a00 + k2*s00;
    L[1] =      k1*a01 + k2*s01;
    L[2] =      k1*a02 + k2*s02;
    L[3] = k0 + k1*a11 + k2*s11;
    L[4] =      k1*a12 + k2*s12;
    L[5] = k0 + k1*a22 + k2*s22;
}

__device__ __forceinline__ void load6(const float* __restrict__ a, float m[6]) {
    m[0] = a[0]; m[1] = a[1]; m[2] = a[2];
    m[3] = a[4]; m[4] = a[5]; m[5] = a[8];
}

__device__ __forceinline__ float fnorm2_diff(const float L1[6], const float L2[6]) {
    float d0 = L1[0]-L2[0], d1 = L1[1]-L2[1], d2 = L1[2]-L2[2];
    float d3 = L1[3]-L2[3], d4 = L1[4]-L2[4], d5 = L1[5]-L2[5];
    return d0*d0 + d3*d3 + d5*d5 + 2.0f * (d1*d1 + d2*d2 + d4*d4);
}

__device__ __forceinline__ void gld_lds16(const float* g, float* l) {
    __builtin_amdgcn_global_load_lds(
        (const __attribute__((address_space(1))) unsigned int*)g,
        (__attribute__((address_space(3))) unsigned int*)l, 16, 0, 0);
}
__device__ __forceinline__ void gld_lds4(const float* g, float* l) {
    __builtin_amdgcn_global_load_lds(
        (const __attribute__((address_space(1))) unsigned int*)g,
        (__attribute__((address_space(3))) unsigned int*)l, 4, 0, 0);
}

// DMA one wave-tile (64 pairs: D1 576 floats + D2 576 floats) into buf.
// 6 VMEM instrs total. LDS dest base is wave-uniform; HW adds lane*size.
__device__ __forceinline__ void issue_wtile(float* buf,
                                            const float* __restrict__ D1,
                                            const float* __restrict__ D2,
                                            long t, int lane) {
    const float* s1 = D1 + t * WTILE_FLOATS;
    const float* s2 = D2 + t * WTILE_FLOATS;
    gld_lds16(s1 +       lane * 4, buf);          // bytes [0,1024)
    gld_lds16(s1 + 256 + lane * 4, buf + 256);    // [1024,2048)
    gld_lds4 (s1 + 512 + lane,     buf + 512);    // [2048,2304)
    gld_lds16(s2 +       lane * 4, buf + 576);
    gld_lds16(s2 + 256 + lane * 4, buf + 832);
    gld_lds4 (s2 + 512 + lane,     buf + 1088);
}

__global__ void __launch_bounds__(BLOCK)
le_partial(const float* __restrict__ D1, const float* __restrict__ D2,
           float* __restrict__ partial, int n) {
    // per-wave private double buffer: no __syncthreads in the hot loop
    __shared__ __align__(16) float lds[NWAVES * 2 * WBUF_FLOATS]; // 36,864 B
    const int tid  = threadIdx.x;
    const int wave = tid >> 6, lane = tid & 63;
    float* wlds = lds + wave * (2 * WBUF_FLOATS);

    const long ntw = n / WPAIRS;                  // full wave-tiles
    const long W   = (long)gridDim.x * NWAVES;    // wave-tile stride
    long t = (long)blockIdx.x * NWAVES + wave;
    float acc = 0.0f;

    if (t < ntw) {
        issue_wtile(wlds, D1, D2, t, lane);       // prologue: buf0 <- tile t
        int cur = 0;
        while (true) {
            long tn = t + W;
            bool hn = (tn < ntw);
            if (hn) issue_wtile(wlds + (cur ^ 1) * WBUF_FLOATS, D1, D2, tn, lane);

            // wait for CURRENT tile's 6 loads; next tile's 6 stay in flight
            if (hn) asm volatile("s_waitcnt vmcnt(6)" ::: "memory");
            else    asm volatile("s_waitcnt vmcnt(0)" ::: "memory");
            __builtin_amdgcn_sched_barrier(0);

            const float* b = wlds + cur * WBUF_FLOATS;
            float m1[6], m2[6], L1[6], L2[6];
            load6(b + lane * 9, m1);
            load6(b + WTILE_FLOATS + lane * 9, m2);
            logm3(m1, L1);
            logm3(m2, L2);
            acc += fnorm2_diff(L1, L2);

            if (!hn) break;
            cur ^= 1;
            t = tn;
        }
    }

    // tail (n % 64 pairs): direct loads by block 0, wave 0
    {
        long base = ntw * WPAIRS;
        if (blockIdx.x == 0 && (long)tid < n - base) {
            long ti = base + tid;
            float m1[6], m2[6], L1[6], L2[6];
            load6(D1 + ti * 9, m1);
            load6(D2 + ti * 9, m2);
            logm3(m1, L1);
            logm3(m2, L2);
            acc += fnorm2_diff(L1, L2);
        }
    }

    // wave reduce (wave = 64)
    #pragma unroll
    for (int off = 32; off > 0; off >>= 1)
        acc += __shfl_down(acc, off, 64);
    __shared__ float wsum[NWAVES];
    if (lane == 0) wsum[wave] = acc;
    __syncthreads();
    if (tid == 0) {
        float s = 0.0f;
        #pragma unroll
        for (int j = 0; j < NWAVES; ++j) s += wsum[j];
        partial[blockIdx.x] = s;
    }
}

__global__ void __launch_bounds__(BLOCK)
le_final(const float* __restrict__ partial, int nparts,
         float* __restrict__ out, double invN) {
    double s = 0.0;
    for (int i = threadIdx.x; i < nparts; i += BLOCK)
        s += (double)partial[i];
    #pragma unroll
    for (int off = 32; off > 0; off >>= 1)
        s += __shfl_down(s, off, 64);
    __shared__ double ws[BLOCK / 64];
    if ((threadIdx.x & 63) == 0) ws[threadIdx.x >> 6] = s;
    __syncthreads();
    if (threadIdx.x == 0) {
        double tt = 0.0;
        #pragma unroll
        for (int i = 0; i < BLOCK / 64; ++i) tt += ws[i];
        out[0] = (float)(tt * invN);
    }
}

extern "C" void kernel_launch(void* const* d_in, const int* in_sizes, int n_in,
                              void* d_out, int out_size, void* d_ws, size_t ws_size,
                              hipStream_t stream) {
    const float* D1 = (const float*)d_in[0];
    const float* D2 = (const float*)d_in[1];
    float* out = (float*)d_out;
    float* partial = (float*)d_ws;

    int n = in_sizes[0] / 9;
    long ntw = n / WPAIRS;

    int grid = 1024;                 // 4 blocks/CU (LDS-limited cap), waves free-run
    long maxg = (ntw + NWAVES - 1) / NWAVES;
    if (maxg > 0 && grid > maxg) grid = (int)maxg;
    int maxblocks = (int)(ws_size / sizeof(float));
    if (maxblocks > 0 && grid > maxblocks) grid = maxblocks;
    if (grid < 1) grid = 1;

    le_partial<<<grid, BLOCK, 0, stream>>>(D1, D2, partial, n);
    le_final<<<1, BLOCK, 0, stream>>>(partial, grid, out, 1.0 / (double)n);
}